// Round 1
// baseline (954.408 us; speedup 1.0000x reference)
//
#include <hip/hip_runtime.h>
#include <hip/hip_bf16.h>

#define NN 50000
#define NE 600000
#define NG 64
#define PD 128
#define HD 256
#define NPAD 50048  // ceil(NN/64)*64

typedef __bf16 bf16;
typedef __bf16 bf16x8 __attribute__((ext_vector_type(8)));
typedef float f32x4 __attribute__((ext_vector_type(4)));

__device__ __forceinline__ float lrelu(float x) { return x > 0.f ? x : 0.01f * x; }

// ---------------- weights -> bf16 ----------------
__global__ void k_convert_weights(const float* __restrict__ pw, const float* __restrict__ w1,
                                  const float* __restrict__ w2, bf16* __restrict__ pw16,
                                  bf16* __restrict__ w116, bf16* __restrict__ w216) {
    int i = blockIdx.x * 256 + threadIdx.x;
    if (i < PD * PD) pw16[i] = (bf16)pw[i];
    if (i < HD * PD) w116[i] = (bf16)w1[i];
    if (i < PD * HD) w216[i] = (bf16)w2[i];
}

// ---------------- GraphNorm stats (batch is sorted) ----------------
__global__ __launch_bounds__(128) void k_gn_stats(const float* __restrict__ x,
                                                  const int* __restrict__ batch,
                                                  float* __restrict__ gsum, float* __restrict__ gsq,
                                                  int* __restrict__ gcnt) {
    int p = threadIdx.x;  // 128
    int base = blockIdx.x * 64;
    int end = min(base + 64, NN);
    float s = 0.f, q = 0.f;
    int cur = batch[base];
    int runstart = base;
    for (int i = base; i < end; ++i) {
        int g = batch[i];
        if (g != cur) {
            atomicAdd(&gsum[cur * PD + p], s);
            atomicAdd(&gsq[cur * PD + p], q);
            if (p == 0) atomicAdd(&gcnt[cur], i - runstart);
            s = 0.f; q = 0.f; cur = g; runstart = i;
        }
        float v = x[(size_t)i * PD + p];
        s += v; q += v * v;
    }
    atomicAdd(&gsum[cur * PD + p], s);
    atomicAdd(&gsq[cur * PD + p], q);
    if (p == 0) atomicAdd(&gcnt[cur], end - runstart);
}

__global__ void k_gn_finalize(const float* __restrict__ gsum, const float* __restrict__ gsq,
                              const int* __restrict__ gcnt, const float* __restrict__ gw,
                              const float* __restrict__ gb, const float* __restrict__ gms,
                              float* __restrict__ gA, float* __restrict__ gB) {
    int i = blockIdx.x * 256 + threadIdx.x;
    if (i >= NG * PD) return;
    int p = i & (PD - 1);
    float c = (float)max(gcnt[i >> 7], 1);
    float m = gsum[i] / c;
    float q = gsq[i] / c;
    float s = gms[p];
    float var = q - m * m * (2.f * s - s * s);
    float inv = rsqrtf(var + 1e-5f);
    float a = gw[p] * inv;
    gA[i] = a;
    gB[i] = gb[p] - a * s * m;
}

__global__ void k_compute_h(const float* __restrict__ x, const int* __restrict__ batch,
                            const float* __restrict__ gA, const float* __restrict__ gB,
                            bf16* __restrict__ h) {
    size_t i = (size_t)blockIdx.x * 256 + threadIdx.x;
    if (i >= (size_t)NN * PD) return;
    int node = (int)(i >> 7), p = (int)(i & (PD - 1));
    int g = batch[node];
    float v = gA[g * PD + p] * x[i] + gB[g * PD + p];
    h[i] = (bf16)lrelu(v);
}

// ---------------- edge BN stats ----------------
__global__ __launch_bounds__(256) void k_bn_stats(const float* __restrict__ ea,
                                                  float* __restrict__ colsum,
                                                  float* __restrict__ colsq) {
    int col = threadIdx.x & (PD - 1), half = threadIdx.x >> 7;
    size_t base = (size_t)blockIdx.x * 512;
    float s = 0.f, q = 0.f;
    for (int r = 0; r < 256; ++r) {
        size_t e = base + (size_t)r * 2 + half;
        if (e < NE) {
            float v = ea[e * PD + col];
            s += v; q += v * v;
        }
    }
    __shared__ float sh[256];
    sh[threadIdx.x] = s;
    __syncthreads();
    if (half == 0) atomicAdd(&colsum[col], s + sh[128 + col]);
    __syncthreads();
    sh[threadIdx.x] = q;
    __syncthreads();
    if (half == 0) atomicAdd(&colsq[col], q + sh[128 + col]);
}

__global__ void k_bn_finalize(const float* __restrict__ colsum, const float* __restrict__ colsq,
                              const float* __restrict__ gamma, const float* __restrict__ beta,
                              float* __restrict__ escale, float* __restrict__ eshift) {
    int p = threadIdx.x;
    float m = colsum[p] / (float)NE;
    float v = colsq[p] / (float)NE - m * m;
    float sc = gamma[p] * rsqrtf(v + 1e-5f);
    escale[p] = sc;
    eshift[p] = beta[p] - sc * m;
}

// ---------------- CSR by dst ----------------
__global__ void k_deg(const int* __restrict__ dst, int* __restrict__ deg) {
    int e = blockIdx.x * 256 + threadIdx.x;
    if (e < NE) atomicAdd(&deg[dst[e]], 1);
}

__global__ __launch_bounds__(1024) void k_scan(const int* __restrict__ deg, int* __restrict__ offs) {
    __shared__ int buf[1024];
    __shared__ int carry;
    if (threadIdx.x == 0) carry = 0;
    __syncthreads();
    for (int base = 0; base < NN; base += 1024) {
        int i = base + threadIdx.x;
        int v = (i < NN) ? deg[i] : 0;
        buf[threadIdx.x] = v;
        __syncthreads();
        for (int s = 1; s < 1024; s <<= 1) {
            int tmp = (threadIdx.x >= s) ? buf[threadIdx.x - s] : 0;
            __syncthreads();
            buf[threadIdx.x] += tmp;
            __syncthreads();
        }
        if (i < NN) offs[i] = carry + buf[threadIdx.x] - v;
        __syncthreads();
        if (threadIdx.x == 0) carry += buf[1023];
        __syncthreads();
    }
}

__global__ void k_scatter(const int* __restrict__ dst, const int* __restrict__ offs,
                          int* __restrict__ cursor, int* __restrict__ perm) {
    int e = blockIdx.x * 256 + threadIdx.x;
    if (e < NE) {
        int d = dst[e];
        int pos = atomicAdd(&cursor[d], 1);
        perm[offs[d] + pos] = e;
    }
}

// ---------------- edge norm + GEMM (attr = leaky(bn(ea)) @ W^T + b), out1 = attr + ea ----------------
template <bool STORE16>
__global__ __launch_bounds__(256) void k_edge_gemm(const float* __restrict__ ea,
                                                   const float* __restrict__ escale,
                                                   const float* __restrict__ eshift,
                                                   const bf16* __restrict__ pw16,
                                                   const float* __restrict__ pass_b,
                                                   bf16* __restrict__ attr16,
                                                   float* __restrict__ out1) {
    __shared__ __align__(16) bf16 A[64 * PD];
    const int t = threadIdx.x;
    const int e0 = blockIdx.x * 64;
    // stage normalized tile (swizzled)
    for (int i = 0; i < 4; ++i) {
        int c = t + i * 256;       // 0..1023
        int row = c >> 4;          // 0..63
        int cb = (c & 15) << 3;    // col base (multiple of 8)
        const float* sp = ea + (size_t)(e0 + row) * PD + cb;
        float4 v0 = *(const float4*)sp;
        float4 v1 = *(const float4*)(sp + 4);
        float4 s0 = *(const float4*)(escale + cb);
        float4 s1 = *(const float4*)(escale + cb + 4);
        float4 f0 = *(const float4*)(eshift + cb);
        float4 f1 = *(const float4*)(eshift + cb + 4);
        bf16x8 pk;
        pk[0] = (bf16)lrelu(fmaf(s0.x, v0.x, f0.x));
        pk[1] = (bf16)lrelu(fmaf(s0.y, v0.y, f0.y));
        pk[2] = (bf16)lrelu(fmaf(s0.z, v0.z, f0.z));
        pk[3] = (bf16)lrelu(fmaf(s0.w, v0.w, f0.w));
        pk[4] = (bf16)lrelu(fmaf(s1.x, v1.x, f1.x));
        pk[5] = (bf16)lrelu(fmaf(s1.y, v1.y, f1.y));
        pk[6] = (bf16)lrelu(fmaf(s1.z, v1.z, f1.z));
        pk[7] = (bf16)lrelu(fmaf(s1.w, v1.w, f1.w));
        *(bf16x8*)&A[(row << 7) + (cb ^ ((row & 7) << 3))] = pk;
    }
    __syncthreads();
    const int wave = t >> 6, lane = t & 63, g = lane >> 4, li = lane & 15;
    const int arow = (wave << 4) + li;
    f32x4 acc[8];
#pragma unroll
    for (int ct = 0; ct < 8; ++ct) acc[ct] = f32x4{0.f, 0.f, 0.f, 0.f};
#pragma unroll
    for (int ks = 0; ks < 4; ++ks) {
        int kb = ks * 32 + g * 8;
        bf16x8 af = *(const bf16x8*)&A[(arow << 7) + (kb ^ ((arow & 7) << 3))];
#pragma unroll
        for (int ct = 0; ct < 8; ++ct) {
            int col = (ct << 4) + li;
            bf16x8 bfr = *(const bf16x8*)(pw16 + col * PD + kb);
            acc[ct] = __builtin_amdgcn_mfma_f32_16x16x32_bf16(af, bfr, acc[ct], 0, 0, 0);
        }
    }
#pragma unroll
    for (int ct = 0; ct < 8; ++ct) {
        int col = (ct << 4) + li;
        float pb = pass_b[col];
#pragma unroll
        for (int j = 0; j < 4; ++j) {
            int row = (wave << 4) + (g << 2) + j;
            size_t idx = (size_t)(e0 + row) * PD + col;
            float v = acc[ct][j] + pb;
            if (STORE16) attr16[idx] = (bf16)v;
            out1[idx] = v + ea[idx];
        }
    }
}

// ---------------- per-node online-softmax aggregation + residual ----------------
template <bool USE16>
__global__ __launch_bounds__(128) void k_aggregate(const int* __restrict__ src,
                                                   const int* __restrict__ offs,
                                                   const int* __restrict__ deg,
                                                   const int* __restrict__ perm,
                                                   const bf16* __restrict__ h,
                                                   const bf16* __restrict__ attr16,
                                                   const float* __restrict__ out1,
                                                   const float* __restrict__ ea,
                                                   const float* __restrict__ tptr,
                                                   bf16* __restrict__ outpre) {
    const int node = blockIdx.x;
    const int p = threadIdx.x;
    const float tv = tptr[0];
    const int o = offs[node], d = deg[node];
    float m = -3.0e38f, den = 0.f, num = 0.f;
    for (int j = 0; j < d; ++j) {
        int e = perm[o + j];
        int s = src[e];
        float av;
        if (USE16) {
            av = (float)attr16[(size_t)e * PD + p];
        } else {
            size_t idx = (size_t)e * PD + p;
            av = out1[idx] - ea[idx];
        }
        float msg = (float)h[(size_t)s * PD + p] + av;
        msg = (msg > 0.f ? msg : 0.f) + 1e-7f;
        float sc = msg * tv;
        float nm = fmaxf(m, sc);
        float esc = __expf(m - nm);
        float w = __expf(sc - nm);
        den = den * esc + w;
        num = num * esc + msg * w;
        m = nm;
    }
    float hv = (float)h[(size_t)node * PD + p];
    float agg = (d > 0) ? num / den : 0.f;
    outpre[(size_t)node * PD + p] = (bf16)(agg + hv);
}

// ---------------- MLP: out0 = relu(LN(outpre @ W1^T)) @ W2^T + x ----------------
__global__ __launch_bounds__(256) void k_mlp(const bf16* __restrict__ outpre,
                                             const bf16* __restrict__ w116,
                                             const bf16* __restrict__ w216,
                                             const float* __restrict__ lng,
                                             const float* __restrict__ lnb,
                                             const float* __restrict__ x,
                                             float* __restrict__ out0) {
    __shared__ __align__(16) bf16 A2[64 * HD];
    const int t = threadIdx.x, wave = t >> 6, lane = t & 63, g = lane >> 4, li = lane & 15;
    const size_t n0 = (size_t)blockIdx.x * 64;
    const int arow = (wave << 4) + li;
    // GEMM1: Y[64][256] = outpre_tile[64][128] @ W1^T
    f32x4 accY[16];
#pragma unroll
    for (int ct = 0; ct < 16; ++ct) accY[ct] = f32x4{0.f, 0.f, 0.f, 0.f};
#pragma unroll
    for (int ks = 0; ks < 4; ++ks) {
        int kb = ks * 32 + g * 8;
        bf16x8 af = *(const bf16x8*)(outpre + (n0 + arow) * PD + kb);
#pragma unroll
        for (int ct = 0; ct < 16; ++ct) {
            int col = (ct << 4) + li;
            bf16x8 bfr = *(const bf16x8*)(w116 + col * PD + kb);
            accY[ct] = __builtin_amdgcn_mfma_f32_16x16x32_bf16(af, bfr, accY[ct], 0, 0, 0);
        }
    }
    // LayerNorm(H) + ReLU -> A2 (swizzled bf16)
#pragma unroll
    for (int j = 0; j < 4; ++j) {
        float s1 = 0.f, s2 = 0.f;
#pragma unroll
        for (int ct = 0; ct < 16; ++ct) {
            float v = accY[ct][j];
            s1 += v; s2 += v * v;
        }
        for (int o = 1; o < 16; o <<= 1) {
            s1 += __shfl_xor(s1, o);
            s2 += __shfl_xor(s2, o);
        }
        float mean = s1 * (1.f / HD);
        float var = s2 * (1.f / HD) - mean * mean;
        float rstd = rsqrtf(var + 1e-5f);
        int row = (wave << 4) + (g << 2) + j;
#pragma unroll
        for (int ct = 0; ct < 16; ++ct) {
            int col = (ct << 4) + li;
            float v = (accY[ct][j] - mean) * rstd;
            v = lng[col] * v + lnb[col];
            v = v > 0.f ? v : 0.f;
            A2[(row << 8) + (col ^ ((row & 7) << 3))] = (bf16)v;
        }
    }
    __syncthreads();
    // GEMM2: Z[64][128] = A2[64][256] @ W2^T
    f32x4 accZ[8];
#pragma unroll
    for (int ct = 0; ct < 8; ++ct) accZ[ct] = f32x4{0.f, 0.f, 0.f, 0.f};
#pragma unroll
    for (int ks = 0; ks < 8; ++ks) {
        int kb = ks * 32 + g * 8;
        bf16x8 af = *(const bf16x8*)&A2[(arow << 8) + (kb ^ ((arow & 7) << 3))];
#pragma unroll
        for (int ct = 0; ct < 8; ++ct) {
            int col = (ct << 4) + li;
            bf16x8 bfr = *(const bf16x8*)(w216 + col * HD + kb);
            accZ[ct] = __builtin_amdgcn_mfma_f32_16x16x32_bf16(af, bfr, accZ[ct], 0, 0, 0);
        }
    }
#pragma unroll
    for (int ct = 0; ct < 8; ++ct) {
        int col = (ct << 4) + li;
#pragma unroll
        for (int j = 0; j < 4; ++j) {
            int row = (wave << 4) + (g << 2) + j;
            size_t n = n0 + row;
            if (n < NN) out0[n * PD + col] = accZ[ct][j] + x[n * PD + col];
        }
    }
}

extern "C" void kernel_launch(void* const* d_in, const int* in_sizes, int n_in,
                              void* d_out, int out_size, void* d_ws, size_t ws_size,
                              hipStream_t stream) {
    const float* x = (const float*)d_in[0];
    const int* ei = (const int*)d_in[1];
    const float* ea = (const float*)d_in[2];
    const int* batch = (const int*)d_in[3];
    const float* gnw = (const float*)d_in[4];
    const float* gnb = (const float*)d_in[5];
    const float* gms = (const float*)d_in[6];
    const float* bng = (const float*)d_in[7];
    const float* bnb = (const float*)d_in[8];
    const float* pW = (const float*)d_in[9];
    const float* pb = (const float*)d_in[10];
    const float* tp = (const float*)d_in[11];
    const float* W1 = (const float*)d_in[12];
    const float* lng = (const float*)d_in[13];
    const float* lnb = (const float*)d_in[14];
    const float* W2 = (const float*)d_in[15];
    const int* srcI = ei;
    const int* dstI = ei + NE;
    float* out0 = (float*)d_out;
    float* out1 = out0 + (size_t)NN * PD;

    char* w = (char*)d_ws;
    size_t off = 0;
    auto alloc = [&](size_t bytes) -> char* {
        char* p = w + off;
        off += (bytes + 255) & ~(size_t)255;
        return p;
    };
    float* gsum = (float*)alloc(NG * PD * 4);
    float* gsq = (float*)alloc(NG * PD * 4);
    float* colsum = (float*)alloc(PD * 4);
    float* colsq = (float*)alloc(PD * 4);
    int* gcnt = (int*)alloc(NG * 4);
    int* deg = (int*)alloc(NN * 4);
    int* cursor = (int*)alloc(NN * 4);
    size_t zero_bytes = off;  // everything above must be zeroed each call
    int* offs = (int*)alloc(NN * 4);
    int* perm = (int*)alloc((size_t)NE * 4);
    float* gA = (float*)alloc(NG * PD * 4);
    float* gB = (float*)alloc(NG * PD * 4);
    float* escale = (float*)alloc(PD * 4);
    float* eshift = (float*)alloc(PD * 4);
    bf16* pw16 = (bf16*)alloc(PD * PD * 2);
    bf16* w116 = (bf16*)alloc(HD * PD * 2);
    bf16* w216 = (bf16*)alloc(PD * HD * 2);
    bf16* h16 = (bf16*)alloc((size_t)NN * PD * 2);
    bf16* outpre = (bf16*)alloc((size_t)NPAD * PD * 2);
    size_t small_total = off;
    bf16* attr16 = (bf16*)alloc((size_t)NE * PD * 2);
    size_t big_total = off;
    if (ws_size < small_total) return;  // cannot run
    const bool big = (ws_size >= big_total);

    hipMemsetAsync(d_ws, 0, zero_bytes, stream);
    k_convert_weights<<<128, 256, 0, stream>>>(pW, W1, W2, pw16, w116, w216);
    k_gn_stats<<<(NN + 63) / 64, 128, 0, stream>>>(x, batch, gsum, gsq, gcnt);
    k_gn_finalize<<<(NG * PD + 255) / 256, 256, 0, stream>>>(gsum, gsq, gcnt, gnw, gnb, gms, gA, gB);
    k_compute_h<<<(NN * PD + 255) / 256, 256, 0, stream>>>(x, batch, gA, gB, h16);
    k_bn_stats<<<(NE + 511) / 512, 256, 0, stream>>>(ea, colsum, colsq);
    k_bn_finalize<<<1, 128, 0, stream>>>(colsum, colsq, bng, bnb, escale, eshift);
    k_deg<<<(NE + 255) / 256, 256, 0, stream>>>(dstI, deg);
    k_scan<<<1, 1024, 0, stream>>>(deg, offs);
    k_scatter<<<(NE + 255) / 256, 256, 0, stream>>>(dstI, offs, cursor, perm);
    if (big) {
        k_edge_gemm<true><<<NE / 64, 256, 0, stream>>>(ea, escale, eshift, pw16, pb, attr16, out1);
        k_aggregate<true><<<NN, 128, 0, stream>>>(srcI, offs, deg, perm, h16, attr16, out1, ea, tp, outpre);
    } else {
        k_edge_gemm<false><<<NE / 64, 256, 0, stream>>>(ea, escale, eshift, pw16, pb, nullptr, out1);
        k_aggregate<false><<<NN, 128, 0, stream>>>(srcI, offs, deg, perm, h16, nullptr, out1, ea, tp, outpre);
    }
    k_mlp<<<NPAD / 64, 256, 0, stream>>>(outpre, w116, w216, lng, lnb, x, out0);
}

// Round 2
// 838.480 us; speedup vs baseline: 1.1383x; 1.1383x over previous
//
#include <hip/hip_runtime.h>
#include <hip/hip_bf16.h>

#define NN 50000
#define NE 600000
#define NG 64
#define PD 128
#define HD 256
#define NPAD 50048   // ceil(NN/64)*64
#define NPART 49     // ceil(NN/1024)

typedef __bf16 bf16;
typedef __bf16 bf16x8 __attribute__((ext_vector_type(8)));
typedef float f32x4 __attribute__((ext_vector_type(4)));

__device__ __forceinline__ float lrelu(float x) { return x > 0.f ? x : 0.01f * x; }

// ---------------- weights -> bf16 ----------------
__global__ void k_convert_weights(const float* __restrict__ pw, const float* __restrict__ w1,
                                  const float* __restrict__ w2, bf16* __restrict__ pw16,
                                  bf16* __restrict__ w116, bf16* __restrict__ w216) {
    int i = blockIdx.x * 256 + threadIdx.x;
    if (i < PD * PD) pw16[i] = (bf16)pw[i];
    if (i < HD * PD) w116[i] = (bf16)w1[i];
    if (i < PD * HD) w216[i] = (bf16)w2[i];
}

// ---------------- GraphNorm stats (batch is sorted) ----------------
__global__ __launch_bounds__(128) void k_gn_stats(const float* __restrict__ x,
                                                  const int* __restrict__ batch,
                                                  float* __restrict__ gsum, float* __restrict__ gsq,
                                                  int* __restrict__ gcnt) {
    int p = threadIdx.x;  // 128
    int base = blockIdx.x * 64;
    int end = min(base + 64, NN);
    float s = 0.f, q = 0.f;
    int cur = batch[base];
    int runstart = base;
    for (int i = base; i < end; ++i) {
        int g = batch[i];
        if (g != cur) {
            atomicAdd(&gsum[cur * PD + p], s);
            atomicAdd(&gsq[cur * PD + p], q);
            if (p == 0) atomicAdd(&gcnt[cur], i - runstart);
            s = 0.f; q = 0.f; cur = g; runstart = i;
        }
        float v = x[(size_t)i * PD + p];
        s += v; q += v * v;
    }
    atomicAdd(&gsum[cur * PD + p], s);
    atomicAdd(&gsq[cur * PD + p], q);
    if (p == 0) atomicAdd(&gcnt[cur], end - runstart);
}

__global__ void k_gn_finalize(const float* __restrict__ gsum, const float* __restrict__ gsq,
                              const int* __restrict__ gcnt, const float* __restrict__ gw,
                              const float* __restrict__ gb, const float* __restrict__ gms,
                              float* __restrict__ gA, float* __restrict__ gB) {
    int i = blockIdx.x * 256 + threadIdx.x;
    if (i >= NG * PD) return;
    int p = i & (PD - 1);
    float c = (float)max(gcnt[i >> 7], 1);
    float m = gsum[i] / c;
    float q = gsq[i] / c;
    float s = gms[p];
    float var = q - m * m * (2.f * s - s * s);
    float inv = rsqrtf(var + 1e-5f);
    float a = gw[p] * inv;
    gA[i] = a;
    gB[i] = gb[p] - a * s * m;
}

__global__ void k_compute_h(const float* __restrict__ x, const int* __restrict__ batch,
                            const float* __restrict__ gA, const float* __restrict__ gB,
                            bf16* __restrict__ h) {
    size_t i = (size_t)blockIdx.x * 256 + threadIdx.x;
    if (i >= (size_t)NN * PD) return;
    int node = (int)(i >> 7), p = (int)(i & (PD - 1));
    int g = batch[node];
    float v = gA[g * PD + p] * x[i] + gB[g * PD + p];
    h[i] = (bf16)lrelu(v);
}

// ---------------- edge BN stats ----------------
__global__ __launch_bounds__(256) void k_bn_stats(const float* __restrict__ ea,
                                                  float* __restrict__ colsum,
                                                  float* __restrict__ colsq) {
    int col = threadIdx.x & (PD - 1), half = threadIdx.x >> 7;
    size_t base = (size_t)blockIdx.x * 512;
    float s = 0.f, q = 0.f;
    for (int r = 0; r < 256; ++r) {
        size_t e = base + (size_t)r * 2 + half;
        if (e < NE) {
            float v = ea[e * PD + col];
            s += v; q += v * v;
        }
    }
    __shared__ float sh[256];
    sh[threadIdx.x] = s;
    __syncthreads();
    if (half == 0) atomicAdd(&colsum[col], s + sh[128 + col]);
    __syncthreads();
    sh[threadIdx.x] = q;
    __syncthreads();
    if (half == 0) atomicAdd(&colsq[col], q + sh[128 + col]);
}

__global__ void k_bn_finalize(const float* __restrict__ colsum, const float* __restrict__ colsq,
                              const float* __restrict__ gamma, const float* __restrict__ beta,
                              float* __restrict__ escale, float* __restrict__ eshift) {
    int p = threadIdx.x;
    float m = colsum[p] / (float)NE;
    float v = colsq[p] / (float)NE - m * m;
    float sc = gamma[p] * rsqrtf(v + 1e-5f);
    escale[p] = sc;
    eshift[p] = beta[p] - sc * m;
}

// ---------------- CSR by dst ----------------
__global__ void k_deg(const int* __restrict__ dst, int* __restrict__ deg) {
    int e = blockIdx.x * 256 + threadIdx.x;
    if (e < NE) atomicAdd(&deg[dst[e]], 1);
}

// hierarchical scan: partial sums -> scan tops -> final offsets
__global__ __launch_bounds__(256) void k_scan_part(const int* __restrict__ deg,
                                                   int* __restrict__ part) {
    __shared__ int sh[256];
    int b = blockIdx.x, t = threadIdx.x;
    int base = b * 1024;
    int s = 0;
#pragma unroll
    for (int k = 0; k < 4; ++k) {
        int i = base + k * 256 + t;
        if (i < NN) s += deg[i];
    }
    sh[t] = s;
    __syncthreads();
    for (int st = 128; st > 0; st >>= 1) {
        if (t < st) sh[t] += sh[t + st];
        __syncthreads();
    }
    if (t == 0) part[b] = sh[0];
}

__global__ void k_scan_tops(const int* __restrict__ part, int* __restrict__ ptot) {
    int t = threadIdx.x;  // 64
    int v = (t < NPART) ? part[t] : 0;
    int orig = v;
    for (int s = 1; s < 64; s <<= 1) {
        int u = __shfl_up(v, s);
        if (t >= s) v += u;
    }
    if (t < NPART) ptot[t] = v - orig;  // exclusive
}

__global__ __launch_bounds__(256) void k_scan_final(const int* __restrict__ deg,
                                                    const int* __restrict__ ptot,
                                                    int* __restrict__ offs) {
    __shared__ int sh[256];
    int b = blockIdx.x, t = threadIdx.x;
    int i0 = b * 1024 + t * 4;
    int v0 = (i0 + 0 < NN) ? deg[i0 + 0] : 0;
    int v1 = (i0 + 1 < NN) ? deg[i0 + 1] : 0;
    int v2 = (i0 + 2 < NN) ? deg[i0 + 2] : 0;
    int v3 = (i0 + 3 < NN) ? deg[i0 + 3] : 0;
    int s = v0 + v1 + v2 + v3;
    sh[t] = s;
    __syncthreads();
    for (int st = 1; st < 256; st <<= 1) {
        int add = (t >= st) ? sh[t - st] : 0;
        __syncthreads();
        sh[t] += add;
        __syncthreads();
    }
    int pre = sh[t] - s + ptot[b];
    if (i0 + 0 < NN) offs[i0 + 0] = pre;
    if (i0 + 1 < NN) offs[i0 + 1] = pre + v0;
    if (i0 + 2 < NN) offs[i0 + 2] = pre + v0 + v1;
    if (i0 + 3 < NN) offs[i0 + 3] = pre + v0 + v1 + v2;
}

__global__ void k_scatter(const int* __restrict__ dst, const int* __restrict__ offs,
                          int* __restrict__ cursor, int* __restrict__ perm) {
    int e = blockIdx.x * 256 + threadIdx.x;
    if (e < NE) {
        int d = dst[e];
        int pos = atomicAdd(&cursor[d], 1);
        perm[offs[d] + pos] = e;
    }
}

// ---------------- edge norm + GEMM (attr = leaky(bn(ea)) @ W^T + b), out1 = attr + ea ----------------
// LDS epilogue round-trip: coalesced float4 / bf16x8 row stores.
template <bool STORE16>
__global__ __launch_bounds__(256) void k_edge_gemm(const float* __restrict__ ea,
                                                   const float* __restrict__ escale,
                                                   const float* __restrict__ eshift,
                                                   const bf16* __restrict__ pw16,
                                                   const float* __restrict__ pass_b,
                                                   bf16* __restrict__ attr16,
                                                   float* __restrict__ out1) {
    __shared__ __align__(16) float R[64][132];  // 33792 B; first 16 KB aliased as bf16 A-tile
    bf16* A = (bf16*)&R[0][0];
    const int t = threadIdx.x;
    const int e0 = blockIdx.x * 64;
    // stage normalized tile (swizzled)
    for (int i = 0; i < 4; ++i) {
        int c = t + i * 256;       // 0..1023
        int row = c >> 4;          // 0..63
        int cb = (c & 15) << 3;    // col base (multiple of 8)
        const float* sp = ea + (size_t)(e0 + row) * PD + cb;
        float4 v0 = *(const float4*)sp;
        float4 v1 = *(const float4*)(sp + 4);
        float4 s0 = *(const float4*)(escale + cb);
        float4 s1 = *(const float4*)(escale + cb + 4);
        float4 f0 = *(const float4*)(eshift + cb);
        float4 f1 = *(const float4*)(eshift + cb + 4);
        bf16x8 pk;
        pk[0] = (bf16)lrelu(fmaf(s0.x, v0.x, f0.x));
        pk[1] = (bf16)lrelu(fmaf(s0.y, v0.y, f0.y));
        pk[2] = (bf16)lrelu(fmaf(s0.z, v0.z, f0.z));
        pk[3] = (bf16)lrelu(fmaf(s0.w, v0.w, f0.w));
        pk[4] = (bf16)lrelu(fmaf(s1.x, v1.x, f1.x));
        pk[5] = (bf16)lrelu(fmaf(s1.y, v1.y, f1.y));
        pk[6] = (bf16)lrelu(fmaf(s1.z, v1.z, f1.z));
        pk[7] = (bf16)lrelu(fmaf(s1.w, v1.w, f1.w));
        *(bf16x8*)&A[(row << 7) + (cb ^ ((row & 7) << 3))] = pk;
    }
    __syncthreads();
    const int wave = t >> 6, lane = t & 63, g = lane >> 4, li = lane & 15;
    const int arow = (wave << 4) + li;
    f32x4 acc[8];
#pragma unroll
    for (int ct = 0; ct < 8; ++ct) acc[ct] = f32x4{0.f, 0.f, 0.f, 0.f};
#pragma unroll
    for (int ks = 0; ks < 4; ++ks) {
        int kb = ks * 32 + g * 8;
        bf16x8 af = *(const bf16x8*)&A[(arow << 7) + (kb ^ ((arow & 7) << 3))];
#pragma unroll
        for (int ct = 0; ct < 8; ++ct) {
            int col = (ct << 4) + li;
            bf16x8 bfr = *(const bf16x8*)(pw16 + col * PD + kb);
            acc[ct] = __builtin_amdgcn_mfma_f32_16x16x32_bf16(af, bfr, acc[ct], 0, 0, 0);
        }
    }
    __syncthreads();  // done reading A; safe to overwrite R
#pragma unroll
    for (int ct = 0; ct < 8; ++ct) {
        int col = (ct << 4) + li;
#pragma unroll
        for (int j = 0; j < 4; ++j) {
            int row = (wave << 4) + (g << 2) + j;
            R[row][col] = acc[ct][j];
        }
    }
    __syncthreads();
    // cooperative coalesced stores: 4 threads per row, 32 floats each
    {
        const int row = t >> 2, q = t & 3;
        const size_t base = (size_t)(e0 + row) * PD + q * 32;
        const float* rp = &R[row][q * 32];
        const float* eap = ea + base;
        float* o1 = out1 + base;
#pragma unroll
        for (int k = 0; k < 4; ++k) {
            float4 r0 = *(const float4*)(rp + k * 8);
            float4 r1 = *(const float4*)(rp + k * 8 + 4);
            float4 b0 = *(const float4*)(pass_b + q * 32 + k * 8);
            float4 b1 = *(const float4*)(pass_b + q * 32 + k * 8 + 4);
            float4 e0v = *(const float4*)(eap + k * 8);
            float4 e1v = *(const float4*)(eap + k * 8 + 4);
            float a0 = r0.x + b0.x, a1 = r0.y + b0.y, a2 = r0.z + b0.z, a3 = r0.w + b0.w;
            float a4 = r1.x + b1.x, a5 = r1.y + b1.y, a6 = r1.z + b1.z, a7 = r1.w + b1.w;
            if (STORE16) {
                bf16x8 pk;
                pk[0] = (bf16)a0; pk[1] = (bf16)a1; pk[2] = (bf16)a2; pk[3] = (bf16)a3;
                pk[4] = (bf16)a4; pk[5] = (bf16)a5; pk[6] = (bf16)a6; pk[7] = (bf16)a7;
                *(bf16x8*)(attr16 + base + k * 8) = pk;
            }
            float4 w0 = {a0 + e0v.x, a1 + e0v.y, a2 + e0v.z, a3 + e0v.w};
            float4 w1 = {a4 + e1v.x, a5 + e1v.y, a6 + e1v.z, a7 + e1v.w};
            *(float4*)(o1 + k * 8) = w0;
            *(float4*)(o1 + k * 8 + 4) = w1;
        }
    }
}

// ---------------- per-node online-softmax aggregation + residual (depth-2 pipelined) ----------------
template <bool USE16>
__global__ __launch_bounds__(128) void k_aggregate(const int* __restrict__ src,
                                                   const int* __restrict__ offs,
                                                   const int* __restrict__ deg,
                                                   const int* __restrict__ perm,
                                                   const bf16* __restrict__ h,
                                                   const bf16* __restrict__ attr16,
                                                   const float* __restrict__ out1,
                                                   const float* __restrict__ ea,
                                                   const float* __restrict__ tptr,
                                                   bf16* __restrict__ outpre) {
    const int node = blockIdx.x;
    const int p = threadIdx.x;
    const float tv = tptr[0];
    const int o = offs[node], d = deg[node];
    float m = -3.0e38f, den = 0.f, num = 0.f;
    float aA = 0.f, hA = 0.f, aB = 0.f, hB = 0.f;
    if (d > 0) {
        int e = perm[o];
        int s = src[e];
        if (USE16) aA = (float)attr16[(size_t)e * PD + p];
        else { size_t idx = (size_t)e * PD + p; aA = out1[idx] - ea[idx]; }
        hA = (float)h[(size_t)s * PD + p];
    }
    if (d > 1) {
        int e = perm[o + 1];
        int s = src[e];
        if (USE16) aB = (float)attr16[(size_t)e * PD + p];
        else { size_t idx = (size_t)e * PD + p; aB = out1[idx] - ea[idx]; }
        hB = (float)h[(size_t)s * PD + p];
    }
    for (int j = 0; j < d; ++j) {
        float av = aA, hv = hA;
        aA = aB; hA = hB;
        if (j + 2 < d) {
            int e = perm[o + j + 2];
            int s = src[e];
            if (USE16) aB = (float)attr16[(size_t)e * PD + p];
            else { size_t idx = (size_t)e * PD + p; aB = out1[idx] - ea[idx]; }
            hB = (float)h[(size_t)s * PD + p];
        }
        float msg = hv + av;
        msg = (msg > 0.f ? msg : 0.f) + 1e-7f;
        float sc = msg * tv;
        float nm = fmaxf(m, sc);
        float esc = __expf(m - nm);
        float w = __expf(sc - nm);
        den = den * esc + w;
        num = num * esc + msg * w;
        m = nm;
    }
    float hv = (float)h[(size_t)node * PD + p];
    float agg = (d > 0) ? num / den : 0.f;
    outpre[(size_t)node * PD + p] = (bf16)(agg + hv);
}

// ---------------- MLP: out0 = relu(LN(outpre @ W1^T)) @ W2^T + x ----------------
__global__ __launch_bounds__(256) void k_mlp(const bf16* __restrict__ outpre,
                                             const bf16* __restrict__ w116,
                                             const bf16* __restrict__ w216,
                                             const float* __restrict__ lng,
                                             const float* __restrict__ lnb,
                                             const float* __restrict__ x,
                                             float* __restrict__ out0) {
    __shared__ __align__(16) float SM[64][132];  // 33792 B; first 32 KB aliased as A2 (64x256 bf16)
    bf16* A2 = (bf16*)&SM[0][0];
    const int t = threadIdx.x, wave = t >> 6, lane = t & 63, g = lane >> 4, li = lane & 15;
    const size_t n0 = (size_t)blockIdx.x * 64;
    const int arow = (wave << 4) + li;
    // GEMM1: Y[64][256] = outpre_tile[64][128] @ W1^T
    f32x4 accY[16];
#pragma unroll
    for (int ct = 0; ct < 16; ++ct) accY[ct] = f32x4{0.f, 0.f, 0.f, 0.f};
#pragma unroll
    for (int ks = 0; ks < 4; ++ks) {
        int kb = ks * 32 + g * 8;
        bf16x8 af = *(const bf16x8*)(outpre + (n0 + arow) * PD + kb);
#pragma unroll
        for (int ct = 0; ct < 16; ++ct) {
            int col = (ct << 4) + li;
            bf16x8 bfr = *(const bf16x8*)(w116 + col * PD + kb);
            accY[ct] = __builtin_amdgcn_mfma_f32_16x16x32_bf16(af, bfr, accY[ct], 0, 0, 0);
        }
    }
    // LayerNorm(H) + ReLU -> A2 (swizzled bf16)
#pragma unroll
    for (int j = 0; j < 4; ++j) {
        float s1 = 0.f, s2 = 0.f;
#pragma unroll
        for (int ct = 0; ct < 16; ++ct) {
            float v = accY[ct][j];
            s1 += v; s2 += v * v;
        }
        for (int o = 1; o < 16; o <<= 1) {
            s1 += __shfl_xor(s1, o);
            s2 += __shfl_xor(s2, o);
        }
        float mean = s1 * (1.f / HD);
        float var = s2 * (1.f / HD) - mean * mean;
        float rstd = rsqrtf(var + 1e-5f);
        int row = (wave << 4) + (g << 2) + j;
#pragma unroll
        for (int ct = 0; ct < 16; ++ct) {
            int col = (ct << 4) + li;
            float v = (accY[ct][j] - mean) * rstd;
            v = lng[col] * v + lnb[col];
            v = v > 0.f ? v : 0.f;
            A2[(row << 8) + (col ^ ((row & 7) << 3))] = (bf16)v;
        }
    }
    __syncthreads();
    // GEMM2: Z[64][128] = A2[64][256] @ W2^T
    f32x4 accZ[8];
#pragma unroll
    for (int ct = 0; ct < 8; ++ct) accZ[ct] = f32x4{0.f, 0.f, 0.f, 0.f};
#pragma unroll
    for (int ks = 0; ks < 8; ++ks) {
        int kb = ks * 32 + g * 8;
        bf16x8 af = *(const bf16x8*)&A2[(arow << 8) + (kb ^ ((arow & 7) << 3))];
#pragma unroll
        for (int ct = 0; ct < 8; ++ct) {
            int col = (ct << 4) + li;
            bf16x8 bfr = *(const bf16x8*)(w216 + col * HD + kb);
            accZ[ct] = __builtin_amdgcn_mfma_f32_16x16x32_bf16(af, bfr, accZ[ct], 0, 0, 0);
        }
    }
    __syncthreads();  // done reading A2
#pragma unroll
    for (int ct = 0; ct < 8; ++ct) {
        int col = (ct << 4) + li;
#pragma unroll
        for (int j = 0; j < 4; ++j) {
            int row = (wave << 4) + (g << 2) + j;
            SM[row][col] = accZ[ct][j];
        }
    }
    __syncthreads();
    {
        const int row = t >> 2, q = t & 3;
        const size_t n = n0 + row;
        if (n < NN) {
            const size_t base = n * PD + q * 32;
            const float* rp = &SM[row][q * 32];
            const float* xp = x + base;
            float* op = out0 + base;
#pragma unroll
            for (int k = 0; k < 8; ++k) {
                float4 r = *(const float4*)(rp + k * 4);
                float4 xv = *(const float4*)(xp + k * 4);
                float4 w = {r.x + xv.x, r.y + xv.y, r.z + xv.z, r.w + xv.w};
                *(float4*)(op + k * 4) = w;
            }
        }
    }
}

extern "C" void kernel_launch(void* const* d_in, const int* in_sizes, int n_in,
                              void* d_out, int out_size, void* d_ws, size_t ws_size,
                              hipStream_t stream) {
    const float* x = (const float*)d_in[0];
    const int* ei = (const int*)d_in[1];
    const float* ea = (const float*)d_in[2];
    const int* batch = (const int*)d_in[3];
    const float* gnw = (const float*)d_in[4];
    const float* gnb = (const float*)d_in[5];
    const float* gms = (const float*)d_in[6];
    const float* bng = (const float*)d_in[7];
    const float* bnb = (const float*)d_in[8];
    const float* pW = (const float*)d_in[9];
    const float* pb = (const float*)d_in[10];
    const float* tp = (const float*)d_in[11];
    const float* W1 = (const float*)d_in[12];
    const float* lng = (const float*)d_in[13];
    const float* lnb = (const float*)d_in[14];
    const float* W2 = (const float*)d_in[15];
    const int* srcI = ei;
    const int* dstI = ei + NE;
    float* out0 = (float*)d_out;
    float* out1 = out0 + (size_t)NN * PD;

    char* w = (char*)d_ws;
    size_t off = 0;
    auto alloc = [&](size_t bytes) -> char* {
        char* p = w + off;
        off += (bytes + 255) & ~(size_t)255;
        return p;
    };
    float* gsum = (float*)alloc(NG * PD * 4);
    float* gsq = (float*)alloc(NG * PD * 4);
    float* colsum = (float*)alloc(PD * 4);
    float* colsq = (float*)alloc(PD * 4);
    int* gcnt = (int*)alloc(NG * 4);
    int* deg = (int*)alloc(NN * 4);
    int* cursor = (int*)alloc(NN * 4);
    size_t zero_bytes = off;  // everything above must be zeroed each call
    int* offs = (int*)alloc(NN * 4);
    int* perm = (int*)alloc((size_t)NE * 4);
    int* part = (int*)alloc(NPART * 4);
    int* ptot = (int*)alloc(NPART * 4);
    float* gA = (float*)alloc(NG * PD * 4);
    float* gB = (float*)alloc(NG * PD * 4);
    float* escale = (float*)alloc(PD * 4);
    float* eshift = (float*)alloc(PD * 4);
    bf16* pw16 = (bf16*)alloc(PD * PD * 2);
    bf16* w116 = (bf16*)alloc(HD * PD * 2);
    bf16* w216 = (bf16*)alloc(PD * HD * 2);
    bf16* h16 = (bf16*)alloc((size_t)NN * PD * 2);
    bf16* outpre = (bf16*)alloc((size_t)NPAD * PD * 2);
    size_t small_total = off;
    bf16* attr16 = (bf16*)alloc((size_t)NE * PD * 2);
    size_t big_total = off;
    if (ws_size < small_total) return;  // cannot run
    const bool big = (ws_size >= big_total);

    hipMemsetAsync(d_ws, 0, zero_bytes, stream);
    k_convert_weights<<<128, 256, 0, stream>>>(pW, W1, W2, pw16, w116, w216);
    k_gn_stats<<<(NN + 63) / 64, 128, 0, stream>>>(x, batch, gsum, gsq, gcnt);
    k_gn_finalize<<<(NG * PD + 255) / 256, 256, 0, stream>>>(gsum, gsq, gcnt, gnw, gnb, gms, gA, gB);
    k_compute_h<<<(NN * PD + 255) / 256, 256, 0, stream>>>(x, batch, gA, gB, h16);
    k_bn_stats<<<(NE + 511) / 512, 256, 0, stream>>>(ea, colsum, colsq);
    k_bn_finalize<<<1, 128, 0, stream>>>(colsum, colsq, bng, bnb, escale, eshift);
    k_deg<<<(NE + 255) / 256, 256, 0, stream>>>(dstI, deg);
    k_scan_part<<<NPART, 256, 0, stream>>>(deg, part);
    k_scan_tops<<<1, 64, 0, stream>>>(part, ptot);
    k_scan_final<<<NPART, 256, 0, stream>>>(deg, ptot, offs);
    k_scatter<<<(NE + 255) / 256, 256, 0, stream>>>(dstI, offs, cursor, perm);
    if (big) {
        k_edge_gemm<true><<<NE / 64, 256, 0, stream>>>(ea, escale, eshift, pw16, pb, attr16, out1);
        k_aggregate<true><<<NN, 128, 0, stream>>>(srcI, offs, deg, perm, h16, attr16, out1, ea, tp, outpre);
    } else {
        k_edge_gemm<false><<<NE / 64, 256, 0, stream>>>(ea, escale, eshift, pw16, pb, nullptr, out1);
        k_aggregate<false><<<NN, 128, 0, stream>>>(srcI, offs, deg, perm, h16, nullptr, out1, ea, tp, outpre);
    }
    k_mlp<<<NPAD / 64, 256, 0, stream>>>(outpre, w116, w216, lng, lnb, x, out0);
}